// Round 7
// baseline (53.257 us; speedup 1.0000x reference)
//
#include <hip/hip_runtime.h>

#define BS 16
#define S  256
#define H  1024
#define T  32

// ws layout (floats): ps[512] | p1[4096*32] | p2[4096*32]
#define PS_OFF 0
#define P1_OFF 512
#define P2_OFF (P1_OFF + BS * S * T)

typedef __bf16 bf16x8 __attribute__((ext_vector_type(8)));
typedef float  f32x4  __attribute__((ext_vector_type(4)));

__device__ inline bf16x8 to_bf8(float4 lo, float4 hi) {
    bf16x8 r;
    r[0] = (__bf16)lo.x; r[1] = (__bf16)lo.y; r[2] = (__bf16)lo.z; r[3] = (__bf16)lo.w;
    r[4] = (__bf16)hi.x; r[5] = (__bf16)hi.y; r[6] = (__bf16)hi.z; r[7] = (__bf16)hi.w;
    return r;
}

// ---------------------------------------------------------------------------
// Kernel A:
//   blk < 128:  ps — one wave per (b,t), coalesced + shfl_xor reduce.
//               (placed FIRST in grid so these short waves drain early)
//   blk >= 128: GEMM, single pass. m-tile = 16 rows (m0=(blk-128)*16); wave w
//     owns output cols [16w,16w+16). K=1024 as 2 chunks of 512 staged in LDS
//     (A-frags from LDS; B-frags from L2-hot W). Chunk-1 global loads issued
//     into regs BEFORE the pre-overwrite barrier -> latency hides under
//     chunk-0 MFMAs. 4 independent acc chains.
// ---------------------------------------------------------------------------
__global__ __launch_bounds__(256) void gemm_ps(
    const float* __restrict__ seq, const float* __restrict__ E,
    const float* __restrict__ W, const float* __restrict__ bias,
    float* __restrict__ ws)
{
    const int tid = threadIdx.x;
    const int lane = tid & 63, wv = tid >> 6;

    if (blockIdx.x < 128) {
        // ---- ps[b,t] = seq[b,:] . W[t,2H:3H] + bias[t], wave-parallel ----
        float* ps = ws + PS_OFF;
        const int o = blockIdx.x * 4 + wv;            // 0..511
        const int bb = o >> 5, t = o & 31;
        const float4* sp = (const float4*)(seq + (size_t)bb * H) + lane * 4;
        const float4* wp = (const float4*)(W + (size_t)t * (3 * H) + 2 * H) + lane * 4;
        float acc = 0.f;
        #pragma unroll
        for (int k = 0; k < 4; ++k) {
            float4 a = sp[k], w = wp[k];
            acc += a.x * w.x + a.y * w.y + a.z * w.z + a.w * w.w;
        }
        #pragma unroll
        for (int m = 32; m >= 1; m >>= 1) acc += __shfl_xor(acc, m);
        if (lane == 0) ps[o] = acc + bias[t];
        return;
    }

    __shared__ __align__(16) float Ef[16][516];       // 33 KB, one 512-k chunk

    const int m0 = (blockIdx.x - 128) * 16;
    const int nb = wv * 16;
    const int wrow = nb + (lane & 15);                // output col 0..63
    const int ksub = (lane >> 4) * 8;                 // k sub-offset 0/8/16/24
    const int erow = lane & 15;

    const float* wbase = W + (size_t)(wrow & 31) * (3 * H)
                           + ((wrow >> 5) ? H : 0) + ksub;

    f32x4 acc[4] = {{0.f,0.f,0.f,0.f},{0.f,0.f,0.f,0.f},
                    {0.f,0.f,0.f,0.f},{0.f,0.f,0.f,0.f}};

    // ---- chunk 0: stage + B-frags ----
    float4 tmp[8];
    #pragma unroll
    for (int i = 0; i < 8; ++i) {                     // 8 coalesced loads, issued b2b
        int f = tid + i * 256, row = f >> 7, c4 = f & 127;
        tmp[i] = *(const float4*)(E + (size_t)(m0 + row) * H + c4 * 4);
    }
    #pragma unroll
    for (int i = 0; i < 8; ++i) {
        int f = tid + i * 256, row = f >> 7, c4 = f & 127;
        *(float4*)&Ef[row][c4 * 4] = tmp[i];
    }
    bf16x8 bf[16];
    #pragma unroll
    for (int s = 0; s < 16; ++s)
        bf[s] = to_bf8(*(const float4*)(wbase + s * 32),
                       *(const float4*)(wbase + s * 32 + 4));
    __syncthreads();

    // ---- chunk 0 MFMAs ----
    #pragma unroll
    for (int s = 0; s < 16; ++s) {
        const float* e = &Ef[erow][s * 32 + ksub];
        bf16x8 a = to_bf8(*(const float4*)e, *(const float4*)(e + 4));
        acc[s & 3] = __builtin_amdgcn_mfma_f32_16x16x32_bf16(a, bf[s], acc[s & 3], 0, 0, 0);
    }

    // ---- chunk 1 global loads into regs (before barrier: hides under MFMAs
    //      of other waves; no LDS touch so ordering is safe) ----
    #pragma unroll
    for (int i = 0; i < 8; ++i) {
        int f = tid + i * 256, row = f >> 7, c4 = f & 127;
        tmp[i] = *(const float4*)(E + (size_t)(m0 + row) * H + 512 + c4 * 4);
    }
    #pragma unroll
    for (int s = 0; s < 16; ++s)
        bf[s] = to_bf8(*(const float4*)(wbase + 512 + s * 32),
                       *(const float4*)(wbase + 512 + s * 32 + 4));

    __syncthreads();                                  // chunk-0 LDS reads done
    #pragma unroll
    for (int i = 0; i < 8; ++i) {
        int f = tid + i * 256, row = f >> 7, c4 = f & 127;
        *(float4*)&Ef[row][c4 * 4] = tmp[i];
    }
    __syncthreads();

    // ---- chunk 1 MFMAs ----
    #pragma unroll
    for (int s = 0; s < 16; ++s) {
        const float* e = &Ef[erow][s * 32 + ksub];
        bf16x8 a = to_bf8(*(const float4*)e, *(const float4*)(e + 4));
        acc[s & 3] = __builtin_amdgcn_mfma_f32_16x16x32_bf16(a, bf[s], acc[s & 3], 0, 0, 0);
    }

    f32x4 sum = (acc[0] + acc[1]) + (acc[2] + acc[3]);

    // ---- store: D layout col=lane&15, row=(lane>>4)*4+r ----
    const int orow = (lane >> 4) * 4;
    float* dst = (nb < 32) ? (ws + P1_OFF) : (ws + P2_OFF);
    const int c = wrow & 31;
    #pragma unroll
    for (int r = 0; r < 4; ++r)
        dst[(size_t)(m0 + orow + r) * T + c] = sum[r];
}

// ---------------------------------------------------------------------------
// Kernel B: out[b,i,j,t] = (p1[b,i,t] + ps[b,t]) + p2[b,j,t]
//   4 rows per block: p2[b] loaded once per 4 output rows (L2 traffic /4).
// ---------------------------------------------------------------------------
__global__ __launch_bounds__(256) void bcast_add(
    const float* __restrict__ ws, float* __restrict__ out)
{
    const int blk = blockIdx.x;                       // 0..1023
    const int b  = blk >> 6;                          // 64 blocks per batch
    const int i0 = (blk & 63) * 4;
    const int tid = threadIdx.x;

    __shared__ __align__(16) float s1[4][32];
    if (tid < 128) {
        int r = tid >> 5, t = tid & 31;
        s1[r][t] = (ws + P1_OFF)[(size_t)(b * S + i0 + r) * T + t]
                 + (ws + PS_OFF)[b * T + t];
    }
    __syncthreads();

    const int t4 = (tid & 7) * 4;
    const float4 s0 = *(const float4*)&s1[0][t4];
    const float4 s1v = *(const float4*)&s1[1][t4];
    const float4 s2 = *(const float4*)&s1[2][t4];
    const float4 s3 = *(const float4*)&s1[3][t4];

    const float4* p2v = (const float4*)(ws + P2_OFF) + (size_t)b * (S * T / 4);
    float4* o0 = (float4*)out + (size_t)(b * S + i0) * (S * T / 4);
    const int RS = S * T / 4;                         // 2048 float4 per row

    #pragma unroll
    for (int k = tid; k < RS; k += 256) {
        float4 v = p2v[k];
        float4 r0, r1, r2, r3;
        r0.x = v.x + s0.x;  r0.y = v.y + s0.y;  r0.z = v.z + s0.z;  r0.w = v.w + s0.w;
        r1.x = v.x + s1v.x; r1.y = v.y + s1v.y; r1.z = v.z + s1v.z; r1.w = v.w + s1v.w;
        r2.x = v.x + s2.x;  r2.y = v.y + s2.y;  r2.z = v.z + s2.z;  r2.w = v.w + s2.w;
        r3.x = v.x + s3.x;  r3.y = v.y + s3.y;  r3.z = v.z + s3.z;  r3.w = v.w + s3.w;
        o0[k]          = r0;
        o0[k + RS]     = r1;
        o0[k + 2 * RS] = r2;
        o0[k + 3 * RS] = r3;
    }
}

extern "C" void kernel_launch(void* const* d_in, const int* in_sizes, int n_in,
                              void* d_out, int out_size, void* d_ws, size_t ws_size,
                              hipStream_t stream)
{
    const float* seq  = (const float*)d_in[0];   // (16,1024)
    const float* E    = (const float*)d_in[1];   // (16,256,1024)
    const float* W    = (const float*)d_in[2];   // (32,3072)
    const float* bias = (const float*)d_in[3];   // (32,)
    float* out = (float*)d_out;                  // (16,256,256,32) f32
    float* ws  = (float*)d_ws;                   // ~1.05 MB used

    gemm_ps<<<384, 256, 0, stream>>>(seq, E, W, bias, ws);
    bcast_add<<<1024, 256, 0, stream>>>(ws, out);
}

// Round 8
// 43.659 us; speedup vs baseline: 1.2198x; 1.2198x over previous
//
#include <hip/hip_runtime.h>

#define BS 16
#define S  256
#define H  1024
#define T  32

// ws layout (floats): ps[512] | p1[4096*32] | p2[4096*32]   (p1,p2 FINAL here)
#define PS_OFF 0
#define P1_OFF 512
#define P2_OFF (P1_OFF + BS * S * T)

typedef __bf16 bf16x8 __attribute__((ext_vector_type(8)));
typedef float  f32x4  __attribute__((ext_vector_type(4)));

__device__ inline bf16x8 to_bf8(float4 lo, float4 hi) {
    bf16x8 r;
    r[0] = (__bf16)lo.x; r[1] = (__bf16)lo.y; r[2] = (__bf16)lo.z; r[3] = (__bf16)lo.w;
    r[4] = (__bf16)hi.x; r[5] = (__bf16)hi.y; r[6] = (__bf16)hi.z; r[7] = (__bf16)hi.w;
    return r;
}

// ---------------------------------------------------------------------------
// Kernel A:
//   blk < 128:  ps — one wave per (b,t) output, coalesced + shfl_xor reduce.
//   blk >= 128: GEMM with INTRA-BLOCK K-split (replaces R5's cross-block
//     KSPLIT + reduce_p kernel):
//       BM=16 rows; wave w owns k-chunk [256w,256w+256) and ALL 64 cols.
//       Per k-step: ONE A-frag (bf16 from LDS, no cvt) feeds 4 MFMAs.
//       E staged as bf16 (33 KB, stride 1032 -> 2-way alias = free).
//       Cross-wave reduce via 16 KB LDS + 1 barrier; p1/p2 written final.
// ---------------------------------------------------------------------------
__global__ __launch_bounds__(256) void gemm_ps(
    const float* __restrict__ seq, const float* __restrict__ E,
    const float* __restrict__ W, const float* __restrict__ bias,
    float* __restrict__ ws)
{
    const int tid = threadIdx.x;
    const int lane = tid & 63, wv = tid >> 6;

    if (blockIdx.x < 128) {
        // ---- ps[b,t] = seq[b,:] . W[t,2H:3H] + bias[t], wave-parallel ----
        float* ps = ws + PS_OFF;
        const int o = blockIdx.x * 4 + wv;            // 0..511
        const int bb = o >> 5, t = o & 31;
        const float4* sp = (const float4*)(seq + (size_t)bb * H) + lane * 4;
        const float4* wp = (const float4*)(W + (size_t)t * (3 * H) + 2 * H) + lane * 4;
        float acc = 0.f;
        #pragma unroll
        for (int k = 0; k < 4; ++k) {
            float4 a = sp[k], w = wp[k];
            acc += a.x * w.x + a.y * w.y + a.z * w.z + a.w * w.w;
        }
        #pragma unroll
        for (int m = 32; m >= 1; m >>= 1) acc += __shfl_xor(acc, m);
        if (lane == 0) ps[o] = acc + bias[t];
        return;
    }

    __shared__ __align__(16) __bf16 Ebf[16][1032];    // 33 KB (pad: 2-way alias)
    __shared__ __align__(16) float  pacc[4][16][64];  // 16 KB partial tiles

    const int m0 = (blockIdx.x - 128) * 16;

    // ---- stage E tile 16x1024 -> bf16 LDS (coalesced 32B/lane reads) ----
    #pragma unroll
    for (int i = 0; i < 8; ++i) {
        int f = tid + i * 256;                        // 0..2047
        int row = f >> 7, c8 = f & 127;
        const float4* src = (const float4*)(E + (size_t)(m0 + row) * H + c8 * 8);
        *(bf16x8*)&Ebf[row][c8 * 8] = to_bf8(src[0], src[1]);
    }

    // ---- B-fragments: all 64 cols x this wave's k-chunk (128 VGPR) ----
    const int kc = wv * 256;
    const int ksub = (lane >> 4) * 8;
    bf16x8 bf[32];
    #pragma unroll
    for (int nt = 0; nt < 4; ++nt) {
        const int col = nt * 16 + (lane & 15);
        const float* wb = W + (size_t)(col & 31) * (3 * H)
                            + ((col >= 32) ? H : 0) + kc + ksub;
        #pragma unroll
        for (int s = 0; s < 8; ++s)
            bf[nt * 8 + s] = to_bf8(*(const float4*)(wb + s * 32),
                                    *(const float4*)(wb + s * 32 + 4));
    }

    __syncthreads();                                  // staging visible

    // ---- 32 MFMAs: 8 k-steps x 4 col-tiles; one A-frag per step ----
    f32x4 acc[4] = {{0.f,0.f,0.f,0.f},{0.f,0.f,0.f,0.f},
                    {0.f,0.f,0.f,0.f},{0.f,0.f,0.f,0.f}};
    const int erow = lane & 15;
    #pragma unroll
    for (int s = 0; s < 8; ++s) {
        bf16x8 a = *(const bf16x8*)&Ebf[erow][kc + s * 32 + ksub];
        acc[0] = __builtin_amdgcn_mfma_f32_16x16x32_bf16(a, bf[s],      acc[0], 0, 0, 0);
        acc[1] = __builtin_amdgcn_mfma_f32_16x16x32_bf16(a, bf[8 + s],  acc[1], 0, 0, 0);
        acc[2] = __builtin_amdgcn_mfma_f32_16x16x32_bf16(a, bf[16 + s], acc[2], 0, 0, 0);
        acc[3] = __builtin_amdgcn_mfma_f32_16x16x32_bf16(a, bf[24 + s], acc[3], 0, 0, 0);
    }

    // ---- partial D tiles -> LDS (D layout: col=lane&15, row=(lane>>4)*4+r) ----
    const int prow = (lane >> 4) * 4;
    #pragma unroll
    for (int nt = 0; nt < 4; ++nt)
        #pragma unroll
        for (int r = 0; r < 4; ++r)
            pacc[wv][prow + r][nt * 16 + (lane & 15)] = acc[nt][r];

    __syncthreads();

    // ---- intra-block reduce over 4 waves; write final p1/p2 ----
    const int col = tid & 63;
    const int r0 = tid >> 6;                          // 0..3
    #pragma unroll
    for (int rr = 0; rr < 4; ++rr) {
        const int row = r0 + rr * 4;
        float v = (pacc[0][row][col] + pacc[1][row][col])
                + (pacc[2][row][col] + pacc[3][row][col]);
        if (col < 32) (ws + P1_OFF)[(size_t)(m0 + row) * T + col] = v;
        else          (ws + P2_OFF)[(size_t)(m0 + row) * T + (col - 32)] = v;
    }
}

// ---------------------------------------------------------------------------
// Kernel B (proven R5/R6 form): out[b,i,j,t] = (p1[b,i,t]+ps[b,t]) + p2[b,j,t]
// One block per (b,i); coalesced float4 stream at the write floor.
// ---------------------------------------------------------------------------
__global__ __launch_bounds__(256) void bcast_add(
    const float* __restrict__ ws, float* __restrict__ out)
{
    const int blk = blockIdx.x;
    const int b = blk >> 8, i = blk & 255;
    const int tid = threadIdx.x;

    __shared__ __align__(16) float s1[32];
    if (tid < 32)
        s1[tid] = (ws + P1_OFF)[(size_t)(b * S + i) * T + tid]
                + (ws + PS_OFF)[b * T + tid];
    __syncthreads();

    const float4 s = *(const float4*)&s1[(tid & 7) * 4];
    const float4* p2v = (const float4*)(ws + P2_OFF) + (size_t)b * (S * T / 4);
    float4* ov = (float4*)out + (size_t)(b * S + i) * (S * T / 4);

    #pragma unroll
    for (int k = tid; k < S * T / 4; k += 256) {
        float4 v = p2v[k];
        float4 r;
        r.x = v.x + s.x; r.y = v.y + s.y; r.z = v.z + s.z; r.w = v.w + s.w;
        ov[k] = r;
    }
}

extern "C" void kernel_launch(void* const* d_in, const int* in_sizes, int n_in,
                              void* d_out, int out_size, void* d_ws, size_t ws_size,
                              hipStream_t stream)
{
    const float* seq  = (const float*)d_in[0];   // (16,1024)
    const float* E    = (const float*)d_in[1];   // (16,256,1024)
    const float* W    = (const float*)d_in[2];   // (32,3072)
    const float* bias = (const float*)d_in[3];   // (32,)
    float* out = (float*)d_out;                  // (16,256,256,32) f32
    float* ws  = (float*)d_ws;                   // ~1.05 MB used

    gemm_ps<<<384, 256, 0, stream>>>(seq, E, W, bias, ws);
    bcast_add<<<BS * S, 256, 0, stream>>>(ws, out);
}

// Round 10
// 37.906 us; speedup vs baseline: 1.4050x; 1.1518x over previous
//
#include <hip/hip_runtime.h>

#define BS 16
#define S  256
#define H  1024
#define T  32
#define KSPLIT 4
#define KCH 256             // k per gemm block
#define BM 32               // rows per gemm block

// ws layout (floats): pp[4][4096][64] | ps[512] | p1[4096*32] | p2[4096*32]
#define PP_OFF 0
#define PP_SZ  (KSPLIT * BS * S * 64)           // 1048576 floats
#define PS_OFF (PP_OFF + PP_SZ)
#define P1_OFF (PS_OFF + 512)
#define P2_OFF (P1_OFF + BS * S * T)

typedef __bf16 bf16x8 __attribute__((ext_vector_type(8)));
typedef float  f32x4  __attribute__((ext_vector_type(4)));

__device__ inline bf16x8 to_bf8(float4 lo, float4 hi) {
    bf16x8 r;
    r[0] = (__bf16)lo.x; r[1] = (__bf16)lo.y; r[2] = (__bf16)lo.z; r[3] = (__bf16)lo.w;
    r[4] = (__bf16)hi.x; r[5] = (__bf16)hi.y; r[6] = (__bf16)hi.z; r[7] = (__bf16)hi.w;
    return r;
}

// ---------------------------------------------------------------------------
// Kernel A (R5 geometry, ps first):
//   blk < 128 : ps — one wave per (b,t), coalesced + shfl_xor reduce.
//   blk >= 128: GEMM partials. g=blk-128: ks=g>>7 (k-chunk of 256),
//     m-tile=32 rows (m0=(g&127)*32); wave w owns cols [16w,16w+16).
//     E tile staged as bf16 (cvt hoisted out of MFMA loop; 17.5 KB LDS,
//     row stride 280 bf16 = 560B: 16B-aligned, ~2-way bank alias = free).
// ---------------------------------------------------------------------------
__global__ __launch_bounds__(256) void gemm_ps(
    const float* __restrict__ seq, const float* __restrict__ E,
    const float* __restrict__ W, const float* __restrict__ bias,
    float* __restrict__ ws)
{
    const int tid = threadIdx.x;
    const int lane = tid & 63, wv = tid >> 6;

    if (blockIdx.x < 128) {
        // ---- ps[b,t] = seq[b,:] . W[t,2H:3H] + bias[t], wave-parallel ----
        float* ps = ws + PS_OFF;
        const int o = blockIdx.x * 4 + wv;            // 0..511
        const int bb = o >> 5, t = o & 31;
        const float4* sp = (const float4*)(seq + (size_t)bb * H) + lane * 4;
        const float4* wp = (const float4*)(W + (size_t)t * (3 * H) + 2 * H) + lane * 4;
        float acc = 0.f;
        #pragma unroll
        for (int k = 0; k < 4; ++k) {
            float4 a = sp[k], w = wp[k];
            acc += a.x * w.x + a.y * w.y + a.z * w.z + a.w * w.w;
        }
        #pragma unroll
        for (int m = 32; m >= 1; m >>= 1) acc += __shfl_xor(acc, m);
        if (lane == 0) ps[o] = acc + bias[t];
        return;
    }

    __shared__ __align__(16) __bf16 Ebf[BM][280];     // 17.5 KB

    const int g = blockIdx.x - 128;
    const int ks = g >> 7;
    const int m0 = (g & 127) * BM;
    const int kbeg = ks * KCH;

    // ---- wave-private B fragments: 16 cols x 256 k (R5-proven volume) ----
    const int nb = wv * 16;
    const int wrow = nb + (lane & 15);                // output col 0..63
    const int ksub = (lane >> 4) * 8;                 // k sub-offset 0/8/16/24
    const float* wbase = W + (size_t)(wrow & 31) * (3 * H)
                           + ((wrow >> 5) ? H : 0) + kbeg + ksub;
    bf16x8 bfrag[8];
    #pragma unroll
    for (int s = 0; s < 8; ++s)
        bfrag[s] = to_bf8(*(const float4*)(wbase + s * 32),
                          *(const float4*)(wbase + s * 32 + 4));

    // ---- stage E tile 32x256 -> bf16 LDS (coalesced 32B/lane reads) ----
    #pragma unroll
    for (int i = 0; i < 4; ++i) {
        int f = tid + i * 256;                        // 0..1023
        int row = f >> 5, c8 = f & 31;                // 32 rows x 32 chunks
        const float4* src = (const float4*)(E + (size_t)(m0 + row) * H
                                            + kbeg + c8 * 8);
        *(bf16x8*)&Ebf[row][c8 * 8] = to_bf8(src[0], src[1]);
    }
    __syncthreads();                                  // the only barrier

    // ---- 16 MFMAs: 2 m-subtiles x 8 k-steps; A-frags straight from LDS ----
    f32x4 acc0 = {0.f,0.f,0.f,0.f}, acc1 = {0.f,0.f,0.f,0.f};
    const int erow = lane & 15;
    #pragma unroll
    for (int s = 0; s < 8; ++s) {
        bf16x8 a0 = *(const bf16x8*)&Ebf[erow][s * 32 + ksub];
        bf16x8 a1 = *(const bf16x8*)&Ebf[erow + 16][s * 32 + ksub];
        acc0 = __builtin_amdgcn_mfma_f32_16x16x32_bf16(a0, bfrag[s], acc0, 0, 0, 0);
        acc1 = __builtin_amdgcn_mfma_f32_16x16x32_bf16(a1, bfrag[s], acc1, 0, 0, 0);
    }

    // ---- store partials: D layout col=lane&15, row=(lane>>4)*4+r ----
    float* pp = ws + PP_OFF + (size_t)ks * (BS * S * 64);
    const int orow = (lane >> 4) * 4;
    const int ocol = nb + (lane & 15);
    #pragma unroll
    for (int r = 0; r < 4; ++r) {
        pp[(size_t)(m0 + orow + r) * 64 + ocol]      = acc0[r];
        pp[(size_t)(m0 + 16 + orow + r) * 64 + ocol] = acc1[r];
    }
}

// ---------------------------------------------------------------------------
// Kernel B: reduce KSPLIT partials; split cols into p1 (ps folded) and p2.
// ---------------------------------------------------------------------------
__global__ __launch_bounds__(256) void reduce_p(float* __restrict__ ws)
{
    const int o = blockIdx.x * 256 + threadIdx.x;     // float4 idx, 0..65535
    const float4* pp = (const float4*)(ws + PP_OFF);
    float4 v = pp[o];
    #pragma unroll
    for (int ks = 1; ks < KSPLIT; ++ks) {
        float4 u = pp[o + ks * (PP_SZ / KSPLIT / 4)];
        v.x += u.x; v.y += u.y; v.z += u.z; v.w += u.w;
    }
    const int row = o >> 4, c4 = o & 15;              // row 0..4095
    if (c4 < 8) {
        const int b = row >> 8;
        float4 s = ((const float4*)(ws + PS_OFF))[b * 8 + c4];
        v.x += s.x; v.y += s.y; v.z += s.z; v.w += s.w;
        ((float4*)(ws + P1_OFF))[row * 8 + c4] = v;
    } else {
        ((float4*)(ws + P2_OFF))[row * 8 + (c4 - 8)] = v;
    }
}

// ---------------------------------------------------------------------------
// Kernel C: out[b,i,j,t] = p1[b,i,t] + p2[b,j,t]   (ps already in p1)
//   No LDS/barrier prologue: s read directly (8x16B segments/wave, L2-hot).
// ---------------------------------------------------------------------------
__global__ __launch_bounds__(256) void bcast_add(
    const float* __restrict__ ws, float* __restrict__ out)
{
    const int blk = blockIdx.x;
    const int b = blk >> 8, i = blk & 255;
    const int tid = threadIdx.x;

    const float4 s = *(const float4*)((ws + P1_OFF)
                     + (size_t)(b * S + i) * T + (tid & 7) * 4);
    const float4* p2v = (const float4*)(ws + P2_OFF) + (size_t)b * (S * T / 4);
    float4* ov = (float4*)out + (size_t)(b * S + i) * (S * T / 4);

    #pragma unroll
    for (int k = tid; k < S * T / 4; k += 256) {
        float4 v = p2v[k];
        float4 r;
        r.x = v.x + s.x; r.y = v.y + s.y; r.z = v.z + s.z; r.w = v.w + s.w;
        ov[k] = r;
    }
}

extern "C" void kernel_launch(void* const* d_in, const int* in_sizes, int n_in,
                              void* d_out, int out_size, void* d_ws, size_t ws_size,
                              hipStream_t stream)
{
    const float* seq  = (const float*)d_in[0];   // (16,1024)
    const float* E    = (const float*)d_in[1];   // (16,256,1024)
    const float* W    = (const float*)d_in[2];   // (32,3072)
    const float* bias = (const float*)d_in[3];   // (32,)
    float* out = (float*)d_out;                  // (16,256,256,32) f32
    float* ws  = (float*)d_ws;                   // ~5.3 MB used

    gemm_ps<<<640, 256, 0, stream>>>(seq, E, W, bias, ws);
    reduce_p<<<256, 256, 0, stream>>>(ws);
    bcast_add<<<BS * S, 256, 0, stream>>>(ws, out);
}